// Round 4
// baseline (127.881 us; speedup 1.0000x reference)
//
#include <hip/hip_runtime.h>
#include <hip/hip_bf16.h>

#define HWv   35840   // H*W = 160*224
#define NPTS  35840
#define Bv    2
#define Kv    16
#define CP3   67
#define COUT  64
#define PPB   16
#define NBLK_PER_B (NPTS / PPB)   // 2240
#define KDIM  1088    // 16 f * 68 c   (c: 0-63 features, 64-66 xyz, 67 pad)
#define ASTR  1096    // sAgg row stride (bf16 elems); 2192 B, 16B-aligned
#define WTSTR 264     // sWt p-stride in f32

typedef __attribute__((ext_vector_type(4))) float  f32x4;
typedef __attribute__((ext_vector_type(8))) short  bf16x8;

static __device__ __forceinline__ unsigned short f2bf(float f) {
    unsigned int u = __float_as_uint(f);
    unsigned int r = (u + 0x7FFFu + ((u >> 16) & 1u)) >> 16;   // RNE
    return (unsigned short)r;
}
static __device__ __forceinline__ float leaky(float v) { return v >= 0.f ? v : 0.1f * v; }

// ---- kernel 1: channel-last bf16 features [B][HW][64] + f32 xyz [B][HW][4] ----
__global__ __launch_bounds__(256) void transpose_kernel(const float* __restrict__ xyz,
                                                        const float* __restrict__ feat,
                                                        unsigned short* __restrict__ feats_bf,
                                                        float* __restrict__ xyz_cl) {
    __shared__ float tile[68][65];
    int t = threadIdx.x;
    int blk = blockIdx.x;                 // Bv * 560
    int b = blk / 560;
    int hw0 = (blk % 560) * 64;
    int j = t & 63, cq = t >> 6;
    for (int cc = 0; cc < 17; ++cc) {
        int c = cc * 4 + cq;              // 0..67
        float v = 0.f;
        if (c < 64)      v = feat[((long)b * 64 + c) * HWv + hw0 + j];
        else if (c < 67) v = xyz[((long)b * 3 + (c - 64)) * HWv + hw0 + j];
        tile[c][j] = v;
    }
    __syncthreads();
    int r = t >> 2, q = t & 3;
    unsigned short* dst = feats_bf + ((long)b * HWv + hw0 + r) * 64;
    #pragma unroll
    for (int i = q; i < 16; i += 4) {
        ushort4 v;
        v.x = f2bf(tile[i * 4 + 0][r]); v.y = f2bf(tile[i * 4 + 1][r]);
        v.z = f2bf(tile[i * 4 + 2][r]); v.w = f2bf(tile[i * 4 + 3][r]);
        *(ushort4*)(dst + i * 4) = v;
    }
    if (q == 0) {
        float4 x4 = make_float4(tile[64][r], tile[65][r], tile[66][r], 0.f);
        *(float4*)(xyz_cl + ((long)b * HWv + hw0 + r) * 4) = x4;
    }
}

// ---- kernel 1b: w_lin -> bf16 [64][1088], channel-remapped to match sAgg ----
__global__ __launch_bounds__(256) void wl_bf16_kernel(const float* __restrict__ w_lin,
                                                      unsigned short* __restrict__ wl_bf) {
    int e = blockIdx.x * 256 + threadIdx.x;   // 64*1088 = 69632
    if (e >= COUT * KDIM) return;
    int o  = e / KDIM;
    int fc = e - o * KDIM;
    int f  = fc / 68;
    int c  = fc - f * 68;
    float v = 0.f;
    if (c < 64)      v = w_lin[o * (16 * CP3) + f * CP3 + 3 + c];    // feature channels
    else if (c < 67) v = w_lin[o * (16 * CP3) + f * CP3 + (c - 64)]; // xyz channels
    wl_bf[e] = f2bf(v);
}

// ---- kernel 2: fused gather + weightnet + agg + MFMA linear ----
__global__ __launch_bounds__(256, 4) void pointconv_main(
        const unsigned short* __restrict__ feats_bf,
        const float*  __restrict__ xyz_cl,
        const unsigned short* __restrict__ wl_bf,
        const int*    __restrict__ knn_idx,
        const int*    __restrict__ mask,
        const float*  __restrict__ sampled,
        const float*  __restrict__ w1,
        const float*  __restrict__ b1,
        const float*  __restrict__ w2,
        const float*  __restrict__ b2,
        const float*  __restrict__ b_lin,
        float*        __restrict__ out) {
    // lifetime-union region: [sXyz 3072 | sWt 16896] overlaid later by sAgg 35072
    __shared__ __align__(16) char sBuf[PPB * ASTR * 2];     // 35072 B
    __shared__ int   sRow[PPB][Kv];
    __shared__ float sMask[PPB][Kv];
    __shared__ float sNx[PPB][4];
    __shared__ float sNet[240];        // w1(24) b1(8) w2(128) b2(16) b_lin(64)

    float* sXyz = (float*)sBuf;                      // [p][k][3]
    float* sWt  = (float*)(sBuf + 3072);             // [p][k*16+f], p-stride 264
    unsigned short* sAgg = (unsigned short*)sBuf;    // [p][1096]

    int t = threadIdx.x;
    int blk = blockIdx.x;
    int b = blk / NBLK_PER_B;
    int n0 = (blk % NBLK_PER_B) * PPB;
    int p = t >> 4, u = t & 15;

    // ---- P0: metadata + params ----
    {
        int base = (b * NPTS + n0 + p) * Kv + u;
        int g = knn_idx[base];
        float mf = mask[base] ? 1.f : 0.f;
        int row = b * HWv + g;
        sRow[p][u]  = row * 128;                     // byte offset into feats_bf
        sMask[p][u] = mf;
        float4 x4 = *(const float4*)(xyz_cl + (long)row * 4);
        float* xd = sXyz + (p * Kv + u) * 3;
        xd[0] = x4.x * mf; xd[1] = x4.y * mf; xd[2] = x4.z * mf;
        if (t < 240) {
            float v;
            if (t < 24)       v = w1[t];
            else if (t < 32)  v = b1[t - 24];
            else if (t < 160) v = w2[t - 32];
            else if (t < 176) v = b2[t - 160];
            else              v = b_lin[t - 176];
            sNet[t] = v;
        }
        if (t < PPB * 3) { int pp = t / 3, c = t - pp * 3; sNx[pp][c] = sampled[(b * 3 + c) * HWv + n0 + pp]; }
    }
    __syncthreads();

    // ---- issue 8-deep gather prefetch NOW; P1 compute hides the latency ----
    const char* fb = (const char*)feats_bf;
    ushort4 pre[8];
    #pragma unroll
    for (int k = 0; k < 8; ++k) pre[k] = *(const ushort4*)(fb + sRow[p][k] + u * 8);

    // ---- P1: weight net, thread = (p,k), h in registers ----
    {
        int k = u;
        const float* W1 = sNet;
        const float* B1 = sNet + 24;
        const float* W2 = sNet + 32;
        const float* B2 = sNet + 160;
        const float* xs = sXyz + (p * Kv + k) * 3;
        float r0 = xs[0] - sNx[p][0];
        float r1 = xs[1] - sNx[p][1];
        float r2 = xs[2] - sNx[p][2];
        float mf = sMask[p][k];
        float h[8];
        #pragma unroll
        for (int i = 0; i < 8; ++i)
            h[i] = leaky(W1[i * 3] * r0 + W1[i * 3 + 1] * r1 + W1[i * 3 + 2] * r2 + B1[i]);
        float wk[16];
        #pragma unroll
        for (int f = 0; f < 16; ++f) {
            float v = B2[f];
            #pragma unroll
            for (int i = 0; i < 8; ++i) v += W2[f * 8 + i] * h[i];
            wk[f] = leaky(v) * mf;                   // mask folded into weight
        }
        f32x4* wdst = (f32x4*)(sWt + p * WTSTR + k * 16);
        wdst[0] = (f32x4){wk[0], wk[1], wk[2], wk[3]};
        wdst[1] = (f32x4){wk[4], wk[5], wk[6], wk[7]};
        wdst[2] = (f32x4){wk[8], wk[9], wk[10], wk[11]};
        wdst[3] = (f32x4){wk[12], wk[13], wk[14], wk[15]};
    }
    __syncthreads();

    // ---- P2: aggregation. thread = (p,u); u owns feature channels 4u..4u+3 ----
    f32x4 agg4[16];
    #pragma unroll
    for (int f = 0; f < 16; ++f) agg4[f] = (f32x4){0.f, 0.f, 0.f, 0.f};
    float ax = 0.f, ay = 0.f, az = 0.f;              // xyz-channel agg (f = u role)

    #pragma unroll
    for (int k = 0; k < Kv; ++k) {
        ushort4 hv = pre[k & 7];
        if (k < 8) pre[k & 7] = *(const ushort4*)(fb + sRow[p][k + 8] + u * 8);
        unsigned int dlo = ((unsigned int)hv.y << 16) | hv.x;
        unsigned int dhi = ((unsigned int)hv.w << 16) | hv.z;
        f32x4 fv4;
        fv4[0] = __uint_as_float(dlo << 16);
        fv4[1] = __uint_as_float(dlo & 0xffff0000u);
        fv4[2] = __uint_as_float(dhi << 16);
        fv4[3] = __uint_as_float(dhi & 0xffff0000u);
        const f32x4* wt4 = (const f32x4*)(sWt + p * WTSTR + k * 16);
        f32x4 w0 = wt4[0], w1v = wt4[1], w2v = wt4[2], w3v = wt4[3];
        agg4[0]  += fv4 * w0[0];  agg4[1]  += fv4 * w0[1];
        agg4[2]  += fv4 * w0[2];  agg4[3]  += fv4 * w0[3];
        agg4[4]  += fv4 * w1v[0]; agg4[5]  += fv4 * w1v[1];
        agg4[6]  += fv4 * w1v[2]; agg4[7]  += fv4 * w1v[3];
        agg4[8]  += fv4 * w2v[0]; agg4[9]  += fv4 * w2v[1];
        agg4[10] += fv4 * w2v[2]; agg4[11] += fv4 * w2v[3];
        agg4[12] += fv4 * w3v[0]; agg4[13] += fv4 * w3v[1];
        agg4[14] += fv4 * w3v[2]; agg4[15] += fv4 * w3v[3];
        // xyz channels: wt[p][k][f=u] * sXyz[p][k][*]
        float wtv = sWt[p * WTSTR + k * 16 + u];
        const float* xs = sXyz + (p * Kv + k) * 3;
        ax += wtv * xs[0]; ay += wtv * xs[1]; az += wtv * xs[2];
    }
    __syncthreads();      // all sWt/sXyz reads done; sAgg may now overlay

    // ---- write agg -> bf16 LDS ----
    {
        #pragma unroll
        for (int f = 0; f < 16; ++f) {
            ushort4 hv;
            hv.x = f2bf(agg4[f][0]); hv.y = f2bf(agg4[f][1]);
            hv.z = f2bf(agg4[f][2]); hv.w = f2bf(agg4[f][3]);
            *(ushort4*)&sAgg[p * ASTR + f * 68 + u * 4] = hv;
        }
        ushort4 hx;
        hx.x = f2bf(ax); hx.y = f2bf(ay); hx.z = f2bf(az); hx.w = 0;
        *(ushort4*)&sAgg[p * ASTR + u * 68 + 64] = hx;   // thread acts as f=u here
    }
    __syncthreads();

    // ---- P3: MFMA  out[16 pts][64 outs] = sAgg[16][1088] x wl_bf[64][1088]^T ----
    {
        int w = t >> 6, l = t & 63;
        int row  = l & 15;
        int kgrp = l >> 4;
        const bf16x8* aptr = (const bf16x8*)&sAgg[row * ASTR + kgrp * 8];
        const bf16x8* bptr = (const bf16x8*)(wl_bf + (w * 16 + row) * KDIM + kgrp * 8);
        f32x4 acc0 = {0.f, 0.f, 0.f, 0.f}, acc1 = {0.f, 0.f, 0.f, 0.f};
        #pragma unroll
        for (int kt = 0; kt < 17; ++kt)
            acc0 = __builtin_amdgcn_mfma_f32_16x16x32_bf16(aptr[kt * 4], bptr[kt * 4], acc0, 0, 0, 0);
        #pragma unroll
        for (int kt = 17; kt < 34; ++kt)
            acc1 = __builtin_amdgcn_mfma_f32_16x16x32_bf16(aptr[kt * 4], bptr[kt * 4], acc1, 0, 0, 0);
        f32x4 acc = acc0 + acc1;
        int o = w * 16 + row;
        float bias = sNet[176 + o];
        float4 res;
        res.x = leaky(acc[0] + bias);
        res.y = leaky(acc[1] + bias);
        res.z = leaky(acc[2] + bias);
        res.w = leaky(acc[3] + bias);
        *(float4*)(out + (long)(b * COUT + o) * HWv + n0 + kgrp * 4) = res;
    }
}

extern "C" void kernel_launch(void* const* d_in, const int* in_sizes, int n_in,
                              void* d_out, int out_size, void* d_ws, size_t ws_size,
                              hipStream_t stream) {
    const float* xyz      = (const float*)d_in[0];
    const float* features = (const float*)d_in[1];
    const float* sampled  = (const float*)d_in[2];
    const int*   knn_idx  = (const int*)  d_in[3];
    const int*   mask     = (const int*)  d_in[4];
    const float* w1       = (const float*)d_in[5];
    const float* b1       = (const float*)d_in[6];
    const float* w2       = (const float*)d_in[7];
    const float* b2       = (const float*)d_in[8];
    const float* w_lin    = (const float*)d_in[9];
    const float* b_lin    = (const float*)d_in[10];
    float* out = (float*)d_out;

    unsigned short* feats_bf = (unsigned short*)d_ws;
    float* xyz_cl = (float*)((char*)d_ws + (size_t)Bv * HWv * 64 * 2);
    unsigned short* wl_bf = (unsigned short*)((char*)xyz_cl + (size_t)Bv * HWv * 4 * 4);

    transpose_kernel<<<Bv * 560, 256, 0, stream>>>(xyz, features, feats_bf, xyz_cl);
    wl_bf16_kernel<<<(COUT * KDIM + 255) / 256, 256, 0, stream>>>(w_lin, wl_bf);
    pointconv_main<<<Bv * NBLK_PER_B, 256, 0, stream>>>(feats_bf, xyz_cl, wl_bf, knn_idx, mask,
                                                        sampled, w1, b1, w2, b2, b_lin, out);
}